// Round 10
// baseline (358.337 us; speedup 1.0000x reference)
//
#include <hip/hip_runtime.h>
#include <hip/hip_bf16.h>
#include <stdint.h>

// Problem constants (B=4096, V=512, H=64)
#define BB 4096
#define VV 512
#define HH 64

typedef short bf16x8 __attribute__((ext_vector_type(8)));
typedef float floatx4 __attribute__((ext_vector_type(4)));
typedef unsigned short ushort8 __attribute__((ext_vector_type(8)));

typedef const __attribute__((address_space(1))) void g_void;
typedef __attribute__((address_space(3))) void l_void;

__device__ __forceinline__ void gload_lds16(const void* g, void* l) {
    __builtin_amdgcn_global_load_lds((g_void*)g, (l_void*)l, 16, 0, 0);
}

__device__ __forceinline__ unsigned short f2bf_rne(float f) {
    unsigned int u = __float_as_uint(f);
    u += 0x7FFFu + ((u >> 16) & 1u);   // round-to-nearest-even
    return (unsigned short)(u >> 16);
}

// ---------------------------------------------------------------- adj only
__global__ __launch_bounds__(256) void adj_kernel(const float* __restrict__ logits,
                                                  float* __restrict__ adj_out) {
    int idx = blockIdx.x * 256 + threadIdx.x;
    int v = idx >> 9, u = idx & (VV - 1);
    adj_out[idx] = (logits[idx] > 0.0f && v != u) ? 1.0f : 0.0f;
}

// ---------------------------------------------------------------- fused prep
// blocks [0, 4096): W1[i][v][h]*adj[v,i] -> bf16 W1t[i][h][v]  (B^T layout)
// blocks [4096, 5120): adj output + X -> packed bf16 Xp
// Xp layout: [rb][ks][mt][lane][8]; lane=quad*16+ln holds
// X[rb*64+mt*16+ln][ks*32+quad*8..+7] => A-frag loads are coalesced 1 KB.
__global__ __launch_bounds__(256) void prep_fused_kernel(
        const float* __restrict__ X, const float* __restrict__ logits,
        const float* __restrict__ W1, float* __restrict__ adj_out,
        unsigned short* __restrict__ Xp, unsigned short* __restrict__ W1t) {
    __shared__ float tile[64][65];   // stride 65: transpose-read conflict-free
    __shared__ float maskv[64];
    int bx = blockIdx.x;
    int t  = threadIdx.x;
    if (bx < 4096) {
        int i  = bx >> 3;
        int v0 = (bx & 7) << 6;
        if (t < 64) {
            int v = v0 + t;
            maskv[t] = (logits[(size_t)v * VV + i] > 0.0f && v != i) ? 1.0f : 0.0f;
        }
        // float4 global loads; scalar LDS writes at stride 65 (2-way, free).
        const float4* src4 = (const float4*)(W1 + ((size_t)i * VV + v0) * HH);
        #pragma unroll
        for (int jj = 0; jj < 4; ++jj) {
            int c  = jj * 256 + t;         // float4 index in [0, 4096)
            int vr = c >> 4, h4 = c & 15;
            float4 w = src4[c];
            tile[vr][h4 * 4 + 0] = w.x;
            tile[vr][h4 * 4 + 1] = w.y;
            tile[vr][h4 * 4 + 2] = w.z;
            tile[vr][h4 * 4 + 3] = w.w;
        }
        __syncthreads();
        unsigned short* dst = W1t + (size_t)i * (HH * VV) + v0;
        #pragma unroll
        for (int j = 0; j < 2; ++j) {
            int c = j * 256 + t;
            int h = c >> 3;
            int vr0 = (c & 7) * 8;
            ushort8 o;
            #pragma unroll
            for (int r = 0; r < 8; ++r)
                o[r] = f2bf_rne(tile[vr0 + r][h] * maskv[vr0 + r]);
            *(ushort8*)&dst[(size_t)h * VV + vr0] = o;
        }
    } else {
        int idx = (bx - 4096) * 256 + t;           // [0, 262144)
        {   // adj: sigmoid(x) > 0.5  <=>  x > 0 ; zero diagonal
            int v = idx >> 9, u = idx & (VV - 1);
            adj_out[idx] = (logits[idx] > 0.0f && v != u) ? 1.0f : 0.0f;
        }
        {   // pack chunk idx (two float4 reads, one 16B store)
            int lane = idx & 63;
            int mt   = (idx >> 6) & 3;
            int ks   = (idx >> 8) & 15;
            int rb   = idx >> 12;
            int row  = rb * 64 + mt * 16 + (lane & 15);
            int k0   = ks * 32 + (lane >> 4) * 8;
            const float4* s4 = (const float4*)(X + (size_t)row * VV + k0);
            float4 a = s4[0], b = s4[1];
            ushort8 o;
            o[0] = f2bf_rne(a.x); o[1] = f2bf_rne(a.y);
            o[2] = f2bf_rne(a.z); o[3] = f2bf_rne(a.w);
            o[4] = f2bf_rne(b.x); o[5] = f2bf_rne(b.y);
            o[6] = f2bf_rne(b.z); o[7] = f2bf_rne(b.w);
            *(ushort8*)(Xp + (size_t)idx * 8) = o;
        }
    }
}

// ---------------------------------------------------------------- main GEMM
// OCCUPANCY x2: single 32 KB B-buffer with mid-block K-reload.
// LDS 33 KB -> 4 blocks/CU (16 waves/CU = 4/SIMD, vs 2/SIMD at 64 KB).
// Flow: stage half0 (k<256) -> barrier -> K-steps 0..7 -> barrier (reads
// done) -> re-stage half1 into SAME buffer -> barrier -> K-steps 8..15.
// The mid-block drain is exposed only to this block's 4 waves; the other
// ~12 resident waves keep the matrix pipe fed (m114 overlap).
// Staging obeys m104/m108: lds addr == c*16, c = j*256 + t (lane-contig).
// i = bx>>4 (measured-best dispatch order, R3/R6 A/B).
__global__ __launch_bounds__(256, 4) void dag_gemm_kernel(
        const unsigned short* __restrict__ Xp,    // packed A frags
        const unsigned short* __restrict__ W1t,   // [V][H][V] bf16 (masked, B^T)
        const float* __restrict__ b1,             // [V][H]
        const float* __restrict__ W2,             // [V][H]
        const float* __restrict__ b2,             // [V]
        float* __restrict__ outT)                 // [V][B] transposed output
{
    __shared__ __align__(16) unsigned short Ws[16384];   // 32 KB: [h][s2], s2 in [0,32)
    __shared__ float Po[256];                            // epilogue gather

    const int t    = threadIdx.x;
    const int wave = t >> 6;
    const int lane = t & 63;
    const int ln   = lane & 15;
    const int quad = lane >> 4;

    const int bx   = blockIdx.x;          // 8192 blocks, i-major (R3 mapping)
    const int i    = bx >> 4;             // 16 consecutive blocks share W1t row i
    const int row0 = (bx & 15) << 8;

    // B-frag fetch: pos = in-half chunk (k/8 units, [0,32)) of row h=nt*16+ln
    auto ldb = [&](int pos, int nt) -> bf16x8 {
        return *(const bf16x8*)&Ws[(nt * 16 + ln) * 256 + ((pos ^ (ln & 7)) * 8)];
    };

    // wave's packed A stream: 64 KB contiguous, frag(ks,mt) at +(ks*4+mt)*512
    const unsigned short* abase =
        Xp + (size_t)((row0 >> 6) + wave) * (64 * VV) + lane * 8;

    // ---- issue first 3 K-steps of A prefetch (oldest in vmem queue)
    bf16x8 af[4][4];
    #pragma unroll
    for (int s = 0; s < 3; ++s)
        #pragma unroll
        for (int mt = 0; mt < 4; ++mt)
            af[s][mt] = *(const bf16x8*)(abase + (s * 4 + mt) * 512);

    // ---- stage W1t k-half0 (32 KB): lds addr = c*16 (lane-contiguous ✓)
    const unsigned short* wbase = W1t + (size_t)i * (HH * VV);
    #pragma unroll
    for (int j = 0; j < 8; ++j) {
        int c = j * 256 + t;              // [0, 2048)
        int h = c >> 5, s2 = c & 31;
        gload_lds16(wbase + (size_t)h * VV + (size_t)(s2 ^ (h & 7)) * 8,
                    (char*)Ws + c * 16);
    }
    __syncthreads();   // drains: half0 staged + af[0..2] complete

    floatx4 acc[4][4];
    #pragma unroll
    for (int a = 0; a < 4; ++a)
        #pragma unroll
        for (int b = 0; b < 4; ++b)
            acc[a][b] = (floatx4){0.f, 0.f, 0.f, 0.f};

    bf16x8 bq[2][4];
    #pragma unroll
    for (int nt = 0; nt < 4; ++nt)
        bq[0][nt] = ldb(quad, nt);

    // ---- K-steps 0..7 (k in [0,256): half0)
    #pragma unroll
    for (int kk = 0; kk < 8; ++kk) {
        #pragma unroll
        for (int mt = 0; mt < 4; ++mt)     // A prefetch for step kk+3
            af[(kk + 3) & 3][mt] =
                *(const bf16x8*)(abase + ((kk + 3) * 4 + mt) * 512);
        if (kk < 7) {                      // B prefetch for step kk+1 (half0)
            #pragma unroll
            for (int nt = 0; nt < 4; ++nt)
                bq[(kk + 1) & 1][nt] = ldb((kk + 1) * 4 + quad, nt);
        }
        #pragma unroll
        for (int mt = 0; mt < 4; ++mt)
            #pragma unroll
            for (int nt = 0; nt < 4; ++nt)
                acc[mt][nt] = __builtin_amdgcn_mfma_f32_16x16x32_bf16(
                    af[kk & 3][mt], bq[kk & 1][nt], acc[mt][nt], 0, 0, 0);
    }

    __syncthreads();   // all waves done READING half0

    // ---- re-stage half1 (k in [256,512)) into the SAME buffer
    #pragma unroll
    for (int j = 0; j < 8; ++j) {
        int c = j * 256 + t;
        int h = c >> 5, s2 = c & 31;
        gload_lds16(wbase + (size_t)h * VV + (size_t)(32 + (s2 ^ (h & 7))) * 8,
                    (char*)Ws + c * 16);
    }
    __syncthreads();   // drains half1 (covered by other resident blocks)

    // B frags for step 8 (pos 0 of new half)
    #pragma unroll
    for (int nt = 0; nt < 4; ++nt)
        bq[0][nt] = ldb(quad, nt);

    // ---- K-steps 8..15 (k in [256,512): half1)
    #pragma unroll
    for (int kk = 8; kk < 16; ++kk) {
        if (kk < 13) {
            #pragma unroll
            for (int mt = 0; mt < 4; ++mt)
                af[(kk + 3) & 3][mt] =
                    *(const bf16x8*)(abase + ((kk + 3) * 4 + mt) * 512);
        }
        if (kk < 15) {
            #pragma unroll
            for (int nt = 0; nt < 4; ++nt)
                bq[(kk + 1) & 1][nt] = ldb(((kk + 1) - 8) * 4 + quad, nt);
        }
        #pragma unroll
        for (int mt = 0; mt < 4; ++mt)
            #pragma unroll
            for (int nt = 0; nt < 4; ++nt)
                acc[mt][nt] = __builtin_amdgcn_mfma_f32_16x16x32_bf16(
                    af[kk & 3][mt], bq[kk & 1][nt], acc[mt][nt], 0, 0, 0);
    }

    // ---- fused epilogue: relu(acc + b1) . W2 + b2, fp32; Po gather is
    //      strictly intra-wave -> no barrier needed before the store.
    float b1v[4], w2v[4];
    #pragma unroll
    for (int nt = 0; nt < 4; ++nt) {
        b1v[nt] = b1[i * HH + nt * 16 + ln];
        w2v[nt] = W2[i * HH + nt * 16 + ln];
    }
    const float b2i = b2[i];
    #pragma unroll
    for (int mt = 0; mt < 4; ++mt) {
        #pragma unroll
        for (int r = 0; r < 4; ++r) {
            float p = 0.f;
            #pragma unroll
            for (int nt = 0; nt < 4; ++nt) {
                float hv = acc[mt][nt][r] + b1v[nt];   // C/D: row=quad*4+r, col=nt*16+ln
                hv = hv > 0.f ? hv : 0.f;
                p += hv * w2v[nt];
            }
            p += __shfl_xor(p, 8);
            p += __shfl_xor(p, 4);
            p += __shfl_xor(p, 2);
            p += __shfl_xor(p, 1);
            if (ln == 0)
                Po[wave * 64 + mt * 16 + quad * 4 + r] = p + b2i;
        }
    }
    outT[(size_t)i * BB + row0 + wave * 64 + lane] = Po[wave * 64 + lane];
}

// ------------------------------------------- outT[V][B] -> out[B][V] transpose
__global__ __launch_bounds__(256) void transpose_kernel(const float* __restrict__ outT,
                                                        float* __restrict__ out) {
    __shared__ float tile[64][65];
    int i0 = (blockIdx.x & 7) * 64;
    int r0 = (blockIdx.x >> 3) * 64;
    int t  = threadIdx.x;
    #pragma unroll
    for (int j = 0; j < 16; ++j) {
        int idx = j * 256 + t;
        int ii = idx >> 6, rr = idx & 63;
        tile[ii][rr] = outT[(size_t)(i0 + ii) * BB + r0 + rr];
    }
    __syncthreads();
    #pragma unroll
    for (int j = 0; j < 16; ++j) {
        int idx = j * 256 + t;
        int rr = idx >> 6, ii = idx & 63;
        out[(size_t)(r0 + rr) * VV + i0 + ii] = tile[ii][rr];
    }
}

// ----------------------------- fallback (no workspace): fp32 vector path
__global__ __launch_bounds__(256) void fallback_kernel(
        const float* __restrict__ X, const float* __restrict__ logits,
        const float* __restrict__ W1, const float* __restrict__ b1,
        const float* __restrict__ W2, const float* __restrict__ b2,
        float* __restrict__ out) {
    __shared__ float Wc[128][64];
    int i   = blockIdx.x & (VV - 1);
    int row = (blockIdx.x >> 9) * 256 + threadIdx.x;
    float acc[64];
    #pragma unroll
    for (int h = 0; h < 64; ++h) acc[h] = 0.f;
    for (int v0 = 0; v0 < VV; v0 += 128) {
        __syncthreads();
        for (int j = 0; j < 32; ++j) {
            int idx = j * 256 + threadIdx.x;
            int vr = idx >> 6, h = idx & 63;
            int v = v0 + vr;
            float m = (logits[(size_t)v * VV + i] > 0.f && v != i) ? 1.f : 0.f;
            Wc[vr][h] = W1[((size_t)i * VV + v) * HH + h] * m;
        }
        __syncthreads();
        for (int vr = 0; vr < 128; ++vr) {
            float xv = X[(size_t)row * VV + v0 + vr];
            #pragma unroll
            for (int h = 0; h < 64; ++h) acc[h] += xv * Wc[vr][h];
        }
    }
    float p = b2[i];
    #pragma unroll
    for (int h = 0; h < 64; ++h) {
        float hv = acc[h] + b1[i * HH + h];
        p += (hv > 0.f ? hv : 0.f) * W2[i * HH + h];
    }
    out[(size_t)row * VV + i] = p;
}

extern "C" void kernel_launch(void* const* d_in, const int* in_sizes, int n_in,
                              void* d_out, int out_size, void* d_ws, size_t ws_size,
                              hipStream_t stream) {
    const float* X      = (const float*)d_in[0];
    const float* logits = (const float*)d_in[1];
    const float* W1     = (const float*)d_in[2];
    const float* b1     = (const float*)d_in[3];
    const float* W2     = (const float*)d_in[4];
    const float* b2     = (const float*)d_in[5];

    float* out     = (float*)d_out;                       // reconstructed [B][V]
    float* adj_out = out + (size_t)BB * VV;               // adj [V][V]

    const size_t xp_bytes   = (size_t)BB * VV * 2;        // 4 MB
    const size_t w1t_bytes  = (size_t)VV * HH * VV * 2;   // 32 MB
    const size_t outt_bytes = (size_t)BB * VV * 4;        // 8 MB
    const size_t need = xp_bytes + w1t_bytes + outt_bytes;

    if (ws_size >= need) {
        unsigned short* Xp   = (unsigned short*)d_ws;
        unsigned short* W1t  = (unsigned short*)((char*)d_ws + xp_bytes);
        float*          outT = (float*)((char*)d_ws + xp_bytes + w1t_bytes);
        hipLaunchKernelGGL(prep_fused_kernel, dim3(5120), dim3(256), 0, stream,
                           X, logits, W1, adj_out, Xp, W1t);
        hipLaunchKernelGGL(dag_gemm_kernel, dim3(8192), dim3(256), 0, stream,
                           Xp, W1t, b1, W2, b2, outT);
        hipLaunchKernelGGL(transpose_kernel, dim3((BB / 64) * (VV / 64)), dim3(256), 0, stream,
                           outT, out);
    } else {
        hipLaunchKernelGGL(adj_kernel, dim3((VV * VV) / 256), dim3(256), 0, stream,
                           logits, adj_out);
        hipLaunchKernelGGL(fallback_kernel, dim3(VV * (BB / 256)), dim3(256), 0, stream,
                           X, logits, W1, b1, W2, b2, out);
    }
}

// Round 11
// 252.873 us; speedup vs baseline: 1.4171x; 1.4171x over previous
//
#include <hip/hip_runtime.h>
#include <hip/hip_bf16.h>
#include <stdint.h>

// Problem constants (B=4096, V=512, H=64)
#define BB 4096
#define VV 512
#define HH 64

typedef short bf16x8 __attribute__((ext_vector_type(8)));
typedef float floatx4 __attribute__((ext_vector_type(4)));
typedef unsigned short ushort8 __attribute__((ext_vector_type(8)));

typedef const __attribute__((address_space(1))) void g_void;
typedef __attribute__((address_space(3))) void l_void;

__device__ __forceinline__ void gload_lds16(const void* g, void* l) {
    __builtin_amdgcn_global_load_lds((g_void*)g, (l_void*)l, 16, 0, 0);
}

__device__ __forceinline__ unsigned short f2bf_rne(float f) {
    unsigned int u = __float_as_uint(f);
    u += 0x7FFFu + ((u >> 16) & 1u);   // round-to-nearest-even
    return (unsigned short)(u >> 16);
}

// ---------------------------------------------------------------- adj only
__global__ __launch_bounds__(256) void adj_kernel(const float* __restrict__ logits,
                                                  float* __restrict__ adj_out) {
    int idx = blockIdx.x * 256 + threadIdx.x;
    int v = idx >> 9, u = idx & (VV - 1);
    adj_out[idx] = (logits[idx] > 0.0f && v != u) ? 1.0f : 0.0f;
}

// ---------------------------------------------------------------- fused prep
// blocks [0, 4096): W1[i][v][h]*adj[v,i] -> bf16 W1t[i][h][v]  (B^T layout)
// blocks [4096, 5120): adj output + X -> packed bf16 Xp
// Xp layout: [rb][ks][mt][lane][8]; lane=quad*16+ln holds
// X[rb*64+mt*16+ln][ks*32+quad*8..+7] => A-frag loads are coalesced 1 KB.
__global__ __launch_bounds__(256) void prep_fused_kernel(
        const float* __restrict__ X, const float* __restrict__ logits,
        const float* __restrict__ W1, float* __restrict__ adj_out,
        unsigned short* __restrict__ Xp, unsigned short* __restrict__ W1t) {
    __shared__ float tile[64][65];   // stride 65: transpose-read conflict-free
    __shared__ float maskv[64];
    int bx = blockIdx.x;
    int t  = threadIdx.x;
    if (bx < 4096) {
        int i  = bx >> 3;
        int v0 = (bx & 7) << 6;
        if (t < 64) {
            int v = v0 + t;
            maskv[t] = (logits[(size_t)v * VV + i] > 0.0f && v != i) ? 1.0f : 0.0f;
        }
        // float4 global loads; scalar LDS writes at stride 65 (2-way, free).
        const float4* src4 = (const float4*)(W1 + ((size_t)i * VV + v0) * HH);
        #pragma unroll
        for (int jj = 0; jj < 4; ++jj) {
            int c  = jj * 256 + t;         // float4 index in [0, 4096)
            int vr = c >> 4, h4 = c & 15;
            float4 w = src4[c];
            tile[vr][h4 * 4 + 0] = w.x;
            tile[vr][h4 * 4 + 1] = w.y;
            tile[vr][h4 * 4 + 2] = w.z;
            tile[vr][h4 * 4 + 3] = w.w;
        }
        __syncthreads();
        unsigned short* dst = W1t + (size_t)i * (HH * VV) + v0;
        #pragma unroll
        for (int j = 0; j < 2; ++j) {
            int c = j * 256 + t;
            int h = c >> 3;
            int vr0 = (c & 7) * 8;
            ushort8 o;
            #pragma unroll
            for (int r = 0; r < 8; ++r)
                o[r] = f2bf_rne(tile[vr0 + r][h] * maskv[vr0 + r]);
            *(ushort8*)&dst[(size_t)h * VV + vr0] = o;
        }
    } else {
        int idx = (bx - 4096) * 256 + t;           // [0, 262144)
        {   // adj: sigmoid(x) > 0.5  <=>  x > 0 ; zero diagonal
            int v = idx >> 9, u = idx & (VV - 1);
            adj_out[idx] = (logits[idx] > 0.0f && v != u) ? 1.0f : 0.0f;
        }
        {   // pack chunk idx (two float4 reads, one 16B store)
            int lane = idx & 63;
            int mt   = (idx >> 6) & 3;
            int ks   = (idx >> 8) & 15;
            int rb   = idx >> 12;
            int row  = rb * 64 + mt * 16 + (lane & 15);
            int k0   = ks * 32 + (lane >> 4) * 8;
            const float4* s4 = (const float4*)(X + (size_t)row * VV + k0);
            float4 a = s4[0], b = s4[1];
            ushort8 o;
            o[0] = f2bf_rne(a.x); o[1] = f2bf_rne(a.y);
            o[2] = f2bf_rne(a.z); o[3] = f2bf_rne(a.w);
            o[4] = f2bf_rne(b.x); o[5] = f2bf_rne(b.y);
            o[6] = f2bf_rne(b.z); o[7] = f2bf_rne(b.w);
            *(ushort8*)(Xp + (size_t)idx * 8) = o;
        }
    }
}

// ---------------------------------------------------------------- main GEMM
// OCCUPANCY 1.5x (spill-free): single 32 KB B-buffer with mid-block K-reload,
// __launch_bounds__(256, 3): register cap 512/3 = 170 >= body footprint
// (~88 arch VGPR + 64 acc AGPR = 152) -> NO spill (R9's (256,4) cap of 128
// crushed to 64 VGPR + 515 MB scratch). LDS 33 KB -> 3 blocks/CU bound by
// registers, 12 waves/CU. Mid-block drain covered by 2 other resident blocks.
// Staging obeys m104/m108: lds addr == c*16, c = j*256 + t (lane-contig).
// i = bx>>4 (measured-best dispatch order, R3/R6 A/B).
__global__ __launch_bounds__(256, 3) void dag_gemm_kernel(
        const unsigned short* __restrict__ Xp,    // packed A frags
        const unsigned short* __restrict__ W1t,   // [V][H][V] bf16 (masked, B^T)
        const float* __restrict__ b1,             // [V][H]
        const float* __restrict__ W2,             // [V][H]
        const float* __restrict__ b2,             // [V]
        float* __restrict__ outT)                 // [V][B] transposed output
{
    __shared__ __align__(16) unsigned short Ws[16384];   // 32 KB: [h][s2], s2 in [0,32)
    __shared__ float Po[256];                            // epilogue gather

    const int t    = threadIdx.x;
    const int wave = t >> 6;
    const int lane = t & 63;
    const int ln   = lane & 15;
    const int quad = lane >> 4;

    const int bx   = blockIdx.x;          // 8192 blocks, i-major (R3 mapping)
    const int i    = bx >> 4;             // 16 consecutive blocks share W1t row i
    const int row0 = (bx & 15) << 8;

    // B-frag fetch: pos = in-half chunk (k/8 units, [0,32)) of row h=nt*16+ln
    auto ldb = [&](int pos, int nt) -> bf16x8 {
        return *(const bf16x8*)&Ws[(nt * 16 + ln) * 256 + ((pos ^ (ln & 7)) * 8)];
    };

    // wave's packed A stream: 64 KB contiguous, frag(ks,mt) at +(ks*4+mt)*512
    const unsigned short* abase =
        Xp + (size_t)((row0 >> 6) + wave) * (64 * VV) + lane * 8;

    // ---- issue first 3 K-steps of A prefetch (oldest in vmem queue)
    bf16x8 af[4][4];
    #pragma unroll
    for (int s = 0; s < 3; ++s)
        #pragma unroll
        for (int mt = 0; mt < 4; ++mt)
            af[s][mt] = *(const bf16x8*)(abase + (s * 4 + mt) * 512);

    // ---- stage W1t k-half0 (32 KB): lds addr = c*16 (lane-contiguous ✓)
    const unsigned short* wbase = W1t + (size_t)i * (HH * VV);
    #pragma unroll
    for (int j = 0; j < 8; ++j) {
        int c = j * 256 + t;              // [0, 2048)
        int h = c >> 5, s2 = c & 31;
        gload_lds16(wbase + (size_t)h * VV + (size_t)(s2 ^ (h & 7)) * 8,
                    (char*)Ws + c * 16);
    }
    __syncthreads();   // drains: half0 staged + af[0..2] complete

    floatx4 acc[4][4];
    #pragma unroll
    for (int a = 0; a < 4; ++a)
        #pragma unroll
        for (int b = 0; b < 4; ++b)
            acc[a][b] = (floatx4){0.f, 0.f, 0.f, 0.f};

    bf16x8 bq[2][4];
    #pragma unroll
    for (int nt = 0; nt < 4; ++nt)
        bq[0][nt] = ldb(quad, nt);

    // ---- K-steps 0..7 (k in [0,256): half0)
    #pragma unroll
    for (int kk = 0; kk < 8; ++kk) {
        #pragma unroll
        for (int mt = 0; mt < 4; ++mt)     // A prefetch for step kk+3
            af[(kk + 3) & 3][mt] =
                *(const bf16x8*)(abase + ((kk + 3) * 4 + mt) * 512);
        if (kk < 7) {                      // B prefetch for step kk+1 (half0)
            #pragma unroll
            for (int nt = 0; nt < 4; ++nt)
                bq[(kk + 1) & 1][nt] = ldb((kk + 1) * 4 + quad, nt);
        }
        #pragma unroll
        for (int mt = 0; mt < 4; ++mt)
            #pragma unroll
            for (int nt = 0; nt < 4; ++nt)
                acc[mt][nt] = __builtin_amdgcn_mfma_f32_16x16x32_bf16(
                    af[kk & 3][mt], bq[kk & 1][nt], acc[mt][nt], 0, 0, 0);
    }

    __syncthreads();   // all waves done READING half0

    // ---- re-stage half1 (k in [256,512)) into the SAME buffer
    #pragma unroll
    for (int j = 0; j < 8; ++j) {
        int c = j * 256 + t;
        int h = c >> 5, s2 = c & 31;
        gload_lds16(wbase + (size_t)h * VV + (size_t)(32 + (s2 ^ (h & 7))) * 8,
                    (char*)Ws + c * 16);
    }
    __syncthreads();   // drains half1 (covered by other resident blocks)

    // B frags for step 8 (pos 0 of new half)
    #pragma unroll
    for (int nt = 0; nt < 4; ++nt)
        bq[0][nt] = ldb(quad, nt);

    // ---- K-steps 8..15 (k in [256,512): half1)
    #pragma unroll
    for (int kk = 8; kk < 16; ++kk) {
        if (kk < 13) {
            #pragma unroll
            for (int mt = 0; mt < 4; ++mt)
                af[(kk + 3) & 3][mt] =
                    *(const bf16x8*)(abase + ((kk + 3) * 4 + mt) * 512);
        }
        if (kk < 15) {
            #pragma unroll
            for (int nt = 0; nt < 4; ++nt)
                bq[(kk + 1) & 1][nt] = ldb(((kk + 1) - 8) * 4 + quad, nt);
        }
        #pragma unroll
        for (int mt = 0; mt < 4; ++mt)
            #pragma unroll
            for (int nt = 0; nt < 4; ++nt)
                acc[mt][nt] = __builtin_amdgcn_mfma_f32_16x16x32_bf16(
                    af[kk & 3][mt], bq[kk & 1][nt], acc[mt][nt], 0, 0, 0);
    }

    // ---- fused epilogue: relu(acc + b1) . W2 + b2, fp32; Po gather is
    //      strictly intra-wave -> no barrier needed before the store.
    float b1v[4], w2v[4];
    #pragma unroll
    for (int nt = 0; nt < 4; ++nt) {
        b1v[nt] = b1[i * HH + nt * 16 + ln];
        w2v[nt] = W2[i * HH + nt * 16 + ln];
    }
    const float b2i = b2[i];
    #pragma unroll
    for (int mt = 0; mt < 4; ++mt) {
        #pragma unroll
        for (int r = 0; r < 4; ++r) {
            float p = 0.f;
            #pragma unroll
            for (int nt = 0; nt < 4; ++nt) {
                float hv = acc[mt][nt][r] + b1v[nt];   // C/D: row=quad*4+r, col=nt*16+ln
                hv = hv > 0.f ? hv : 0.f;
                p += hv * w2v[nt];
            }
            p += __shfl_xor(p, 8);
            p += __shfl_xor(p, 4);
            p += __shfl_xor(p, 2);
            p += __shfl_xor(p, 1);
            if (ln == 0)
                Po[wave * 64 + mt * 16 + quad * 4 + r] = p + b2i;
        }
    }
    outT[(size_t)i * BB + row0 + wave * 64 + lane] = Po[wave * 64 + lane];
}

// ------------------------------------------- outT[V][B] -> out[B][V] transpose
__global__ __launch_bounds__(256) void transpose_kernel(const float* __restrict__ outT,
                                                        float* __restrict__ out) {
    __shared__ float tile[64][65];
    int i0 = (blockIdx.x & 7) * 64;
    int r0 = (blockIdx.x >> 3) * 64;
    int t  = threadIdx.x;
    #pragma unroll
    for (int j = 0; j < 16; ++j) {
        int idx = j * 256 + t;
        int ii = idx >> 6, rr = idx & 63;
        tile[ii][rr] = outT[(size_t)(i0 + ii) * BB + r0 + rr];
    }
    __syncthreads();
    #pragma unroll
    for (int j = 0; j < 16; ++j) {
        int idx = j * 256 + t;
        int rr = idx >> 6, ii = idx & 63;
        out[(size_t)(r0 + rr) * VV + i0 + ii] = tile[ii][rr];
    }
}

// ----------------------------- fallback (no workspace): fp32 vector path
__global__ __launch_bounds__(256) void fallback_kernel(
        const float* __restrict__ X, const float* __restrict__ logits,
        const float* __restrict__ W1, const float* __restrict__ b1,
        const float* __restrict__ W2, const float* __restrict__ b2,
        float* __restrict__ out) {
    __shared__ float Wc[128][64];
    int i   = blockIdx.x & (VV - 1);
    int row = (blockIdx.x >> 9) * 256 + threadIdx.x;
    float acc[64];
    #pragma unroll
    for (int h = 0; h < 64; ++h) acc[h] = 0.f;
    for (int v0 = 0; v0 < VV; v0 += 128) {
        __syncthreads();
        for (int j = 0; j < 32; ++j) {
            int idx = j * 256 + threadIdx.x;
            int vr = idx >> 6, h = idx & 63;
            int v = v0 + vr;
            float m = (logits[(size_t)v * VV + i] > 0.f && v != i) ? 1.f : 0.f;
            Wc[vr][h] = W1[((size_t)i * VV + v) * HH + h] * m;
        }
        __syncthreads();
        for (int vr = 0; vr < 128; ++vr) {
            float xv = X[(size_t)row * VV + v0 + vr];
            #pragma unroll
            for (int h = 0; h < 64; ++h) acc[h] += xv * Wc[vr][h];
        }
    }
    float p = b2[i];
    #pragma unroll
    for (int h = 0; h < 64; ++h) {
        float hv = acc[h] + b1[i * HH + h];
        p += (hv > 0.f ? hv : 0.f) * W2[i * HH + h];
    }
    out[(size_t)row * VV + i] = p;
}

extern "C" void kernel_launch(void* const* d_in, const int* in_sizes, int n_in,
                              void* d_out, int out_size, void* d_ws, size_t ws_size,
                              hipStream_t stream) {
    const float* X      = (const float*)d_in[0];
    const float* logits = (const float*)d_in[1];
    const float* W1     = (const float*)d_in[2];
    const float* b1     = (const float*)d_in[3];
    const float* W2     = (const float*)d_in[4];
    const float* b2     = (const float*)d_in[5];

    float* out     = (float*)d_out;                       // reconstructed [B][V]
    float* adj_out = out + (size_t)BB * VV;               // adj [V][V]

    const size_t xp_bytes   = (size_t)BB * VV * 2;        // 4 MB
    const size_t w1t_bytes  = (size_t)VV * HH * VV * 2;   // 32 MB
    const size_t outt_bytes = (size_t)BB * VV * 4;        // 8 MB
    const size_t need = xp_bytes + w1t_bytes + outt_bytes;

    if (ws_size >= need) {
        unsigned short* Xp   = (unsigned short*)d_ws;
        unsigned short* W1t  = (unsigned short*)((char*)d_ws + xp_bytes);
        float*          outT = (float*)((char*)d_ws + xp_bytes + w1t_bytes);
        hipLaunchKernelGGL(prep_fused_kernel, dim3(5120), dim3(256), 0, stream,
                           X, logits, W1, adj_out, Xp, W1t);
        hipLaunchKernelGGL(dag_gemm_kernel, dim3(8192), dim3(256), 0, stream,
                           Xp, W1t, b1, W2, b2, outT);
        hipLaunchKernelGGL(transpose_kernel, dim3((BB / 64) * (VV / 64)), dim3(256), 0, stream,
                           outT, out);
    } else {
        hipLaunchKernelGGL(adj_kernel, dim3((VV * VV) / 256), dim3(256), 0, stream,
                           logits, adj_out);
        hipLaunchKernelGGL(fallback_kernel, dim3(VV * (BB / 256)), dim3(256), 0, stream,
                           X, logits, W1, b1, W2, b2, out);
    }
}